// Round 6
// baseline (158.828 us; speedup 1.0000x reference)
//
#include <hip/hip_runtime.h>
#include <math.h>

#define KTOP 200
#define NPART 32
#define NHIST 2048
#define CAND_CAP 512
#define WCAP 512
#define CLIST_CAP 1536   // expected qualifiers ~650/vehicle; big margin
#define SRANK_MIN 64u
#define NCHUNK 8
#define K0B 256
#define K1B 256
#define K2B 512
#define BLOCK 512        // mono fallback block
#define SAMPLE_MAX 2048

// d2 exactly as numpy: ((dx*dx + dy*dy) + dz*dz), no fma contraction
__device__ __forceinline__ float d2_ref(float ax, float ay, float az,
                                        float bx, float by, float bz) {
    float dx = __fsub_rn(ax, bx), dy = __fsub_rn(ay, by), dz = __fsub_rn(az, bz);
    return __fadd_rn(__fadd_rn(__fmul_rn(dx, dx), __fmul_rn(dy, dy)), __fmul_rn(dz, dz));
}

__device__ __forceinline__ unsigned key2(float cx, float cy, float cz,
                                         float px, float py, float pz) {
    return __float_as_uint(d2_ref(cx, cy, cz, px, py, pz));
}

__device__ __forceinline__ unsigned key_of(const float* __restrict__ fus, int j,
                                           float vx, float vy, float vz) {
    return __float_as_uint(d2_ref(vx, vy, vz, fus[3*j], fus[3*j+1], fus[3*j+2]));
}

// shape-context bin of rel = p_j - q0, mirroring the reference f32 math
__device__ __forceinline__ int compute_bin(float rx, float ry, float rz) {
    const float TWO_PI_F = (float)6.283185307179586;
    const float PI_F     = (float)3.141592653589793;
    const float XY_W     = (float)(6.283185307179586 / 4.0);
    const float ZY_W     = (float)(3.141592653589793 / 4.0);

    float d2 = __fadd_rn(__fadd_rn(__fmul_rn(rx, rx), __fmul_rn(ry, ry)), __fmul_rn(rz, rz));
    float D  = sqrtf(__fadd_rn(d2, 1e-7f));
    float dist_bin;
    if (D >= 4.0f)      dist_bin = 1.0f;
    else if (D >= 1.0f) dist_bin = 0.0f;
    else                return -1;

    float axy = fmodf(atan2f(ry, rx) + TWO_PI_F, TWO_PI_F);
    float azy = fmodf(atan2f(ry, rz) + TWO_PI_F, PI_F);
    float xyb = floorf(__fdiv_rn(axy, XY_W));
    float zyb = floorf(__fdiv_rn(azy, ZY_W));
    if (!(xyb >= 0.0f && zyb >= 0.0f)) return -1;
    float ab  = xyb * 4.0f + zyb;
    int bin = (int)(dist_bin * 16.0f + ab);
    return bin;
}

// parallel "find bucket where cumulative count crosses remq" over hist[NHIST]
// leaves *s_bucket = 0xFFFFFFFF if the cumulative never reaches remq
template<int B>
__device__ __forceinline__ void find_bucket_dev(const unsigned* __restrict__ hist,
                                                unsigned remq,
                                                unsigned* waveTot, unsigned* waveBase,
                                                unsigned* s_bucket, unsigned* s_rem,
                                                unsigned* s_bcount, int tid) {
    const int lane = tid & 63, wid = tid >> 6;
    if (tid == 0) *s_bucket = 0xFFFFFFFFu;
    const int PER = NHIST / B;
    int base = tid * PER;
    unsigned p = 0;
    #pragma unroll
    for (int i = 0; i < PER; i++) p += hist[base + i];
    unsigned incl = p;
    #pragma unroll
    for (int d = 1; d < 64; d <<= 1) {
        unsigned n = __shfl_up(incl, d, 64);
        if (lane >= d) incl += n;
    }
    if (lane == 63) waveTot[wid] = incl;
    __syncthreads();
    if (tid == 0) {
        unsigned acc = 0;
        for (int w = 0; w < B / 64; w++) { waveBase[w] = acc; acc += waveTot[w]; }
    }
    __syncthreads();
    unsigned excl = waveBase[wid] + incl - p;
    if (excl < remq && remq <= excl + p) {
        unsigned cum = excl;
        #pragma unroll
        for (int i = 0; i < PER; i++) {
            unsigned c = hist[base + i];
            if (cum + c >= remq) { *s_bucket = base + i; *s_rem = remq - cum; *s_bcount = c; break; }
            cum += c;
        }
    }
    __syncthreads();
}

// ---------------- k0a: planarize fus (AoS -> 3 planes, float4-padded) ----------------
__global__ void planarize_kernel(const float* __restrict__ fus,
                                 float* __restrict__ fx, float* __restrict__ fy,
                                 float* __restrict__ fz, int nfus, int padN) {
    int j = blockIdx.x * blockDim.x + threadIdx.x;
    if (j < nfus) {
        fx[j] = fus[3*j]; fy[j] = fus[3*j+1]; fz[j] = fus[3*j+2];
    } else if (j < padN) {
        fx[j] = 0.f; fy[j] = 0.f; fz[j] = 0.f;
    }
}

// ---------------- k0b: per-vehicle sample -> conservative bound maxKey[v]; zero count ----------------
__global__ __launch_bounds__(K0B, 8)
void sample_bound_kernel(const float* __restrict__ veh,
                         const float* __restrict__ fx, const float* __restrict__ fy,
                         const float* __restrict__ fz,
                         unsigned* __restrict__ mk, int* __restrict__ cnt, int nfus) {
    const int v = blockIdx.x;
    const int tid = threadIdx.x;
    __shared__ unsigned hist[NHIST];
    __shared__ unsigned waveTot[K0B/64], waveBase[K0B/64];
    __shared__ unsigned s_bucket, s_rem, s_bcount;

    const float vx = veh[v*3], vy = veh[v*3+1], vz = veh[v*3+2];
    for (int i = tid; i < NHIST; i += K0B) hist[i] = 0;
    __syncthreads();
    const int S = (nfus < SAMPLE_MAX) ? nfus : SAMPLE_MAX;
    for (int j = tid; j < S; j += K0B) {
        unsigned k = key2(vx, vy, vz, fx[j], fy[j], fz[j]);
        atomicAdd(&hist[k >> 21], 1u);
    }
    __syncthreads();
    unsigned srank;
    if (S >= nfus) srank = KTOP;   // sample is the whole population -> exact
    else {
        unsigned s2 = (unsigned)((3LL * KTOP * S + nfus - 1) / nfus);
        srank = (s2 < SRANK_MIN) ? SRANK_MIN : s2;
    }
    find_bucket_dev<K0B>(hist, srank, waveTot, waveBase, &s_bucket, &s_rem, &s_bcount, tid);
    if (tid == 0) {
        unsigned e = (s_bucket < NHIST) ? s_bucket : (NHIST - 1);  // unset -> filter off
        mk[v] = ((e + 1u) << 21) - 1u;   // all keys <= mk lie in buckets <= e
        cnt[v] = 0;
    }
}

// ---------------- k1: pure stream filter, no LDS, no barriers ----------------
__global__ __launch_bounds__(K1B, 8)
void stream_filter_kernel(const float* __restrict__ veh,
                          const float4* __restrict__ fx4, const float4* __restrict__ fy4,
                          const float4* __restrict__ fz4,
                          const unsigned* __restrict__ mk, int* __restrict__ cnt,
                          unsigned long long* __restrict__ clG, int nfus, int ppc) {
    const int bx = blockIdx.x;
    const int v  = bx / NCHUNK;
    const int c  = bx - v * NCHUNK;
    const int tid = threadIdx.x;
    const int lane = tid & 63;
    const float vx = veh[v*3], vy = veh[v*3+1], vz = veh[v*3+2];
    const unsigned maxKey = mk[v];
    unsigned long long* cl = clG + (size_t)v * CLIST_CAP;
    int* cp = cnt + v;
    const int pbase = c * ppc;
    int pend = pbase + ppc; if (pend > nfus) pend = nfus;

    for (int p4 = (pbase >> 2) + tid; (p4 << 2) < pend; p4 += K1B) {
        const int j0 = p4 << 2;
        float4 X = fx4[p4], Y = fy4[p4], Z = fz4[p4];
        unsigned k0 = key2(vx, vy, vz, X.x, Y.x, Z.x);
        unsigned k1 = key2(vx, vy, vz, X.y, Y.y, Z.y);
        unsigned k2 = key2(vx, vy, vz, X.z, Y.z, Z.z);
        unsigned k3 = key2(vx, vy, vz, X.w, Y.w, Z.w);
        bool q0 = (k0 <= maxKey);
        bool q1 = (k1 <= maxKey) && (j0 + 1 < pend);
        bool q2 = (k2 <= maxKey) && (j0 + 2 < pend);
        bool q3 = (k3 <= maxKey) && (j0 + 3 < pend);
        // loop-exit drops HIGH lanes first (p4 grows with lane) => lane 0 active
        // whenever any lane of this wave is, so the lane-0 atomic is safe.
        unsigned long long m0 = __ballot(q0), m1 = __ballot(q1);
        unsigned long long m2 = __ballot(q2), m3 = __ballot(q3);
        if (m0 | m1 | m2 | m3) {            // wave-uniform branch
            int c0 = __popcll(m0), c1 = __popcll(m1), c2 = __popcll(m2);
            int tot = c0 + c1 + c2 + __popcll(m3);
            int base = 0;
            if (lane == 0) base = atomicAdd(cp, tot);   // device-scope global atomic
            base = __shfl(base, 0, 64);
            const unsigned long long lt = (1ull << lane) - 1ull;
            int o0 = base + (int)__popcll(m0 & lt);
            int o1 = base + c0 + (int)__popcll(m1 & lt);
            int o2 = base + c0 + c1 + (int)__popcll(m2 & lt);
            int o3 = base + c0 + c1 + c2 + (int)__popcll(m3 & lt);
            if (q0 && o0 < CLIST_CAP) cl[o0] = ((unsigned long long)k0 << 32) | (unsigned)(j0 + 0);
            if (q1 && o1 < CLIST_CAP) cl[o1] = ((unsigned long long)k1 << 32) | (unsigned)(j0 + 1);
            if (q2 && o2 < CLIST_CAP) cl[o2] = ((unsigned long long)k2 << 32) | (unsigned)(j0 + 2);
            if (q3 && o3 < CLIST_CAP) cl[o3] = ((unsigned long long)k3 << 32) | (unsigned)(j0 + 3);
        }
    }
}

// ---------------- k2: per-vehicle exact selection + binning + softmax ----------------
__global__ __launch_bounds__(K2B, 8)
void select_bin_kernel(const float* __restrict__ veh,
                       const float* __restrict__ fx, const float* __restrict__ fy,
                       const float* __restrict__ fz,
                       const unsigned* __restrict__ mk, const int* __restrict__ cntArr,
                       const unsigned long long* __restrict__ clG,
                       float* __restrict__ out, int nfus) {
    const int v = blockIdx.x;
    const int tid = threadIdx.x;
    const int lane = tid & 63;

    __shared__ unsigned hist[NHIST];
    __shared__ unsigned long long clistS[CLIST_CAP];
    __shared__ unsigned long long cand[CAND_CAP];
    __shared__ int wlist[WCAP];
    __shared__ unsigned hist32[NPART];
    __shared__ unsigned waveTot[K2B/64], waveBase[K2B/64];
    __shared__ unsigned s_bucket, s_rem, s_bcount;
    __shared__ int s_candCount, s_wcount;
    __shared__ float s_q0[3];
    __shared__ unsigned long long s_minPacked, s_lowBound;

    const float vx = veh[v*3], vy = veh[v*3+1], vz = veh[v*3+2];
    const unsigned maxKey = mk[v];
    const unsigned E = maxKey >> 21;
    const int cnRaw = cntArr[v];
    const bool noOvf = (cnRaw <= CLIST_CAP);
    const int cn = noOvf ? cnRaw : CLIST_CAP;
    const unsigned long long* clg = clG + (size_t)v * CLIST_CAP;

    if (tid == 0) { s_minPacked = ~0ull; s_candCount = 0; s_wcount = 0; }
    if (tid < NPART) hist32[tid] = 0;
    for (int i = tid; i < NHIST; i += K2B) hist[i] = 0;
    for (int i = tid; i < cn; i += K2B) clistS[i] = clg[i];
    __syncthreads();
    if (noOvf) {
        // clist is the exact multiset of keys with bucket <= E -> hist exact on [0,E], zero above
        for (int i = tid; i < cn; i += K2B) atomicAdd(&hist[(unsigned)(clistS[i] >> 53)], 1u);
    }
    __syncthreads();

    find_bucket_dev<K2B>(hist, KTOP, waveTot, waveBase, &s_bucket, &s_rem, &s_bcount, tid);
    unsigned T = s_bucket, rem = s_rem, bcount = s_bcount;
    int shift = 21;
    const bool fastOK = noOvf && (T <= E);   // unset (0xFFFFFFFF) fails

    if (fastOK) {
        // argmin (= top-1, always bucket <= E, always in clist)
        unsigned long long lm = ~0ull;
        for (int i = tid; i < cn; i += K2B) { unsigned long long p = clistS[i]; lm = (p < lm) ? p : lm; }
        #pragma unroll
        for (int d = 32; d > 0; d >>= 1) {
            unsigned long long o = __shfl_xor(lm, d, 64);
            lm = (o < lm) ? o : lm;
        }
        if (lane == 0) atomicMin(&s_minPacked, lm);
        __syncthreads();
    } else {
        // rare: bound failed or clist overflowed -> rebuild full exact histogram + argmin
        for (int i = tid; i < NHIST; i += K2B) hist[i] = 0;
        __syncthreads();
        unsigned long long lm = ~0ull;
        for (int j = tid; j < nfus; j += K2B) {
            unsigned k = key2(vx, vy, vz, fx[j], fy[j], fz[j]);
            atomicAdd(&hist[k >> 21], 1u);
            unsigned long long p = ((unsigned long long)k << 32) | (unsigned)j;
            lm = (p < lm) ? p : lm;
        }
        #pragma unroll
        for (int d = 32; d > 0; d >>= 1) {
            unsigned long long o = __shfl_xor(lm, d, 64);
            lm = (o < lm) ? o : lm;
        }
        if (lane == 0) atomicMin(&s_minPacked, lm);
        __syncthreads();
        find_bucket_dev<K2B>(hist, KTOP, waveTot, waveBase, &s_bucket, &s_rem, &s_bcount, tid);
        T = s_bucket; rem = s_rem; bcount = s_bcount;
    }

    if (tid == 0) {
        int i0 = (int)(s_minPacked & 0xFFFFFFFFull);
        s_q0[0] = fx[i0]; s_q0[1] = fy[i0]; s_q0[2] = fz[i0];
    }
    __syncthreads();
    const float q0x = s_q0[0], q0y = s_q0[1], q0z = s_q0[2];

    // rare: refine threshold bucket if too many candidates (reload-based)
    while (bcount > CAND_CAP && shift > 0) {
        int newshift = (shift > 11) ? (shift - 11) : 0;
        unsigned digmask = (1u << (shift - newshift)) - 1;
        for (int i = tid; i < NHIST; i += K2B) hist[i] = 0;
        __syncthreads();
        for (int j = tid; j < nfus; j += K2B) {
            unsigned k = key2(vx, vy, vz, fx[j], fy[j], fz[j]);
            if ((k >> shift) == T) atomicAdd(&hist[(k >> newshift) & digmask], 1u);
        }
        __syncthreads();
        find_bucket_dev<K2B>(hist, rem, waveTot, waveBase, &s_bucket, &s_rem, &s_bcount, tid);
        T = (T << (shift - newshift)) | s_bucket;
        rem = s_rem;
        bcount = s_bcount;
        shift = newshift;
    }

    // scan B: winners -> wlist, boundary bucket -> cand
    if (fastOK && shift == 21) {
        for (int i = tid; i < cn; i += K2B) {
            unsigned long long p = clistS[i];
            unsigned hi = (unsigned)(p >> 53);   // == key >> 21
            if (hi < T) {
                int pos = atomicAdd(&s_wcount, 1);
                if (pos < WCAP) wlist[pos] = (int)(p & 0xFFFFFFFFull);
            } else if (hi == T) {
                int pos = atomicAdd(&s_candCount, 1);
                if (pos < CAND_CAP) cand[pos] = p;
            }
        }
    } else {
        for (int j = tid; j < nfus; j += K2B) {
            unsigned k = key2(vx, vy, vz, fx[j], fy[j], fz[j]);
            unsigned hi = k >> shift;
            if (hi < T) { int pos = atomicAdd(&s_wcount, 1); if (pos < WCAP) wlist[pos] = j; }
            else if (hi == T) { int pos = atomicAdd(&s_candCount, 1); if (pos < CAND_CAP) cand[pos] = ((unsigned long long)k << 32) | (unsigned)j; }
        }
    }
    __syncthreads();

    const int cnt2 = s_candCount;
    if (cnt2 <= CAND_CAP) {
        // exact stable ranking among boundary candidates by (key, idx)
        for (int i = tid; i < cnt2; i += K2B) {
            unsigned long long me = cand[i];
            int rank = 0;
            for (int k2i = 0; k2i < cnt2; k2i++) rank += (cand[k2i] < me) ? 1 : 0;
            if (rank < (int)rem) {
                int pos = atomicAdd(&s_wcount, 1);
                if (pos < WCAP) wlist[pos] = (int)(me & 0xFFFFFFFFull);
            }
        }
    }
    __syncthreads();

    // compact winner processing
    {
        int wc = s_wcount; if (wc > WCAP) wc = WCAP;
        for (int i = tid; i < wc; i += K2B) {
            int j = wlist[i];
            int bin = compute_bin(__fsub_rn(fx[j], q0x), __fsub_rn(fy[j], q0y), __fsub_rn(fz[j], q0z));
            if (bin >= 0 && bin < NPART) atomicAdd(&hist32[bin], 1u);
        }
    }
    __syncthreads();

    if (cnt2 > CAND_CAP) {
        // pathological fallback: serial extraction of `rem` smallest in bucket T
        if (tid == 0) s_lowBound = 0;
        __syncthreads();
        for (unsigned itx = 0; itx < rem; ++itx) {
            if (tid == 0) s_minPacked = ~0ull;
            __syncthreads();
            unsigned long long lowB = s_lowBound;
            unsigned long long lm = ~0ull;
            for (int j = tid; j < nfus; j += K2B) {
                unsigned k = key2(vx, vy, vz, fx[j], fy[j], fz[j]);
                if ((k >> shift) == T) {
                    unsigned long long p = ((unsigned long long)k << 32) | (unsigned)j;
                    if (p >= lowB && p < lm) lm = p;
                }
            }
            #pragma unroll
            for (int d = 32; d > 0; d >>= 1) {
                unsigned long long o = __shfl_xor(lm, d, 64);
                lm = (o < lm) ? o : lm;
            }
            if (lane == 0) atomicMin(&s_minPacked, lm);
            __syncthreads();
            if (tid == 0) {
                int jm = (int)(s_minPacked & 0xFFFFFFFFull);
                int bin = compute_bin(__fsub_rn(fx[jm], q0x), __fsub_rn(fy[jm], q0y), __fsub_rn(fz[jm], q0z));
                if (bin >= 0 && bin < NPART) hist32[bin] += 1u;
                s_lowBound = s_minPacked + 1;
            }
            __syncthreads();
        }
    }

    // epilogue (32 lanes of wave 0): counts+1 -> L2-normalize*4 -> softmax
    if (tid < NPART) {
        float c = (float)hist32[tid] + 1.0f;
        float ss = __fmul_rn(c, c);
        #pragma unroll
        for (int d = 16; d > 0; d >>= 1) ss += __shfl_xor(ss, d, 64);
        float vv = __fmul_rn(__fdiv_rn(c, sqrtf(ss)), 4.0f);
        float mx = vv;
        #pragma unroll
        for (int d = 16; d > 0; d >>= 1) mx = fmaxf(mx, __shfl_xor(mx, d, 64));
        float e = expf(vv - mx);
        float sum = e;
        #pragma unroll
        for (int d = 16; d > 0; d >>= 1) sum += __shfl_xor(sum, d, 64);
        out[v * NPART + tid] = __fdiv_rn(e, sum);
    }
}

// ---------------- monolithic fallback (r5 kernel, used only if workspace too small) ----------------
__global__ __launch_bounds__(BLOCK, 8)
void shape_context_mono(const float* __restrict__ veh,
                        const float* __restrict__ fus,
                        float* __restrict__ out,
                        int nfus) {
    const int b   = blockIdx.x;
    const int tid = threadIdx.x;
    const int lane = tid & 63;
    const int wid  = tid >> 6;

    __shared__ unsigned int hist[NHIST];
    __shared__ unsigned long long clist[CLIST_CAP];
    __shared__ unsigned long long cand[CAND_CAP];
    __shared__ int wlist[WCAP];
    __shared__ unsigned int hist32[NPART];
    __shared__ unsigned int waveTot[BLOCK / 64];
    __shared__ unsigned int waveBase[BLOCK / 64];
    __shared__ unsigned int s_bucket, s_rem, s_bcount;
    __shared__ int s_candCount, s_wcount, s_clistCount;
    __shared__ float s_q0[3];
    __shared__ unsigned long long s_minPacked, s_lowBound;

    const float vx = veh[b * 3 + 0], vy = veh[b * 3 + 1], vz = veh[b * 3 + 2];
    const float4* fus4 = (const float4*)fus;
    const int ntrip = nfus >> 2;

    if (tid == 0) { s_minPacked = ~0ull; s_candCount = 0; s_wcount = 0; s_clistCount = 0; }
    for (int i = tid; i < NHIST; i += BLOCK) hist[i] = 0;
    if (tid < NPART) hist32[tid] = 0;
    __syncthreads();

    auto push_l = [&](unsigned k, unsigned j) {
        int pos = atomicAdd(&s_clistCount, 1);
        if (pos < CLIST_CAP) clist[pos] = ((unsigned long long)k << 32) | j;
    };

    unsigned k0 = 0, k1 = 0, k2 = 0, k3 = 0;
    const bool t0v = (tid < ntrip);
    if (t0v) {
        float4 A = fus4[3 * tid], Bq = fus4[3 * tid + 1], Cq = fus4[3 * tid + 2];
        k0 = __float_as_uint(d2_ref(vx, vy, vz, A.x,  A.y,  A.z));
        k1 = __float_as_uint(d2_ref(vx, vy, vz, A.w,  Bq.x, Bq.y));
        k2 = __float_as_uint(d2_ref(vx, vy, vz, Bq.z, Bq.w, Cq.x));
        k3 = __float_as_uint(d2_ref(vx, vy, vz, Cq.y, Cq.z, Cq.w));
        atomicAdd(&hist[k0 >> 21], 1u);
        atomicAdd(&hist[k1 >> 21], 1u);
        atomicAdd(&hist[k2 >> 21], 1u);
        atomicAdd(&hist[k3 >> 21], 1u);
    }
    __syncthreads();

    unsigned srank;
    {
        long long sample = (long long)((ntrip < BLOCK) ? ntrip : BLOCK) * 4;
        if (sample >= (long long)nfus) srank = KTOP;
        else {
            unsigned s2 = (unsigned)(((long long)3 * KTOP * sample + nfus - 1) / nfus);
            srank = (s2 < SRANK_MIN) ? SRANK_MIN : s2;
        }
    }
    find_bucket_dev<BLOCK>(hist, srank, waveTot, waveBase, &s_bucket, &s_rem, &s_bcount, tid);
    const unsigned E = (s_bucket < NHIST) ? s_bucket : (NHIST - 1);
    const unsigned maxKey = ((E + 1u) << 21) - 1u;

    if (t0v) {
        unsigned jb = 4u * (unsigned)tid;
        if (k0 <= maxKey) push_l(k0, jb + 0);
        if (k1 <= maxKey) push_l(k1, jb + 1);
        if (k2 <= maxKey) push_l(k2, jb + 2);
        if (k3 <= maxKey) push_l(k3, jb + 3);
    }

    {
        int m = BLOCK + tid;
        bool valid = (m < ntrip);
        float4 A, Bq, Cq;
        if (valid) { A = fus4[3 * m]; Bq = fus4[3 * m + 1]; Cq = fus4[3 * m + 2]; }
        while (valid) {
            const int mn = m + BLOCK;
            const bool vnext = (mn < ntrip);
            float4 An, Bn, Cn;
            if (vnext) { An = fus4[3 * mn]; Bn = fus4[3 * mn + 1]; Cn = fus4[3 * mn + 2]; }

            unsigned q0k = __float_as_uint(d2_ref(vx, vy, vz, A.x,  A.y,  A.z));
            unsigned q1k = __float_as_uint(d2_ref(vx, vy, vz, A.w,  Bq.x, Bq.y));
            unsigned q2k = __float_as_uint(d2_ref(vx, vy, vz, Bq.z, Bq.w, Cq.x));
            unsigned q3k = __float_as_uint(d2_ref(vx, vy, vz, Cq.y, Cq.z, Cq.w));
            unsigned long long m0 = __ballot(q0k <= maxKey);
            unsigned long long m1 = __ballot(q1k <= maxKey);
            unsigned long long m2 = __ballot(q2k <= maxKey);
            unsigned long long m3 = __ballot(q3k <= maxKey);
            if (m0 | m1 | m2 | m3) {
                int c0 = __popcll(m0), c1 = __popcll(m1), c2 = __popcll(m2);
                int tot = c0 + c1 + c2 + __popcll(m3);
                int base = 0;
                if (lane == 0) base = atomicAdd(&s_clistCount, tot);
                base = __shfl(base, 0, 64);
                const unsigned long long lt = (1ull << lane) - 1ull;
                unsigned jb = 4u * (unsigned)m;
                int o0 = base + (int)__popcll(m0 & lt);
                int o1 = base + c0 + (int)__popcll(m1 & lt);
                int o2 = base + c0 + c1 + (int)__popcll(m2 & lt);
                int o3 = base + c0 + c1 + c2 + (int)__popcll(m3 & lt);
                if (q0k <= maxKey && o0 < CLIST_CAP) clist[o0] = ((unsigned long long)q0k << 32) | (jb + 0);
                if (q1k <= maxKey && o1 < CLIST_CAP) clist[o1] = ((unsigned long long)q1k << 32) | (jb + 1);
                if (q2k <= maxKey && o2 < CLIST_CAP) clist[o2] = ((unsigned long long)q2k << 32) | (jb + 2);
                if (q3k <= maxKey && o3 < CLIST_CAP) clist[o3] = ((unsigned long long)q3k << 32) | (jb + 3);
            }
            A = An; Bq = Bn; Cq = Cn; m = mn; valid = vnext;
        }
    }
    for (int j = (nfus & ~3) + tid; j < nfus; j += BLOCK) {
        unsigned k = key_of(fus, j, vx, vy, vz);
        if (k <= maxKey) push_l(k, (unsigned)j);
    }
    __syncthreads();

    const int cnRaw = s_clistCount;
    const bool noOvf = (cnRaw <= CLIST_CAP);
    if (noOvf) {
        for (int i = tid; i <= (int)E; i += BLOCK) hist[i] = 0;
        __syncthreads();
        for (int i = tid; i < cnRaw; i += BLOCK)
            atomicAdd(&hist[(unsigned)(clist[i] >> 53)], 1u);
        __syncthreads();
    }

    find_bucket_dev<BLOCK>(hist, KTOP, waveTot, waveBase, &s_bucket, &s_rem, &s_bcount, tid);
    unsigned T = s_bucket;
    unsigned rem = s_rem;
    unsigned bcount = s_bcount;
    int shift = 21;
    const bool fastOK = noOvf && (T <= E);

    if (fastOK) {
        unsigned long long lm = ~0ull;
        for (int i = tid; i < cnRaw; i += BLOCK) { unsigned long long p = clist[i]; lm = (p < lm) ? p : lm; }
        #pragma unroll
        for (int d = 32; d > 0; d >>= 1) {
            unsigned long long o = __shfl_xor(lm, d, 64);
            lm = (o < lm) ? o : lm;
        }
        if (lane == 0) atomicMin(&s_minPacked, lm);
        __syncthreads();
    } else {
        for (int i = tid; i < NHIST; i += BLOCK) hist[i] = 0;
        __syncthreads();
        unsigned long long lm = ~0ull;
        for (int j = tid; j < nfus; j += BLOCK) {
            unsigned k = key_of(fus, j, vx, vy, vz);
            atomicAdd(&hist[k >> 21], 1u);
            unsigned long long p = ((unsigned long long)k << 32) | (unsigned)j;
            lm = (p < lm) ? p : lm;
        }
        #pragma unroll
        for (int d = 32; d > 0; d >>= 1) {
            unsigned long long o = __shfl_xor(lm, d, 64);
            lm = (o < lm) ? o : lm;
        }
        if (lane == 0) atomicMin(&s_minPacked, lm);
        __syncthreads();
        find_bucket_dev<BLOCK>(hist, KTOP, waveTot, waveBase, &s_bucket, &s_rem, &s_bcount, tid);
        T = s_bucket; rem = s_rem; bcount = s_bcount;
    }

    if (tid == 0) {
        int idx0 = (int)(s_minPacked & 0xFFFFFFFFull);
        s_q0[0] = fus[idx0 * 3]; s_q0[1] = fus[idx0 * 3 + 1]; s_q0[2] = fus[idx0 * 3 + 2];
    }
    __syncthreads();
    const float q0x = s_q0[0], q0y = s_q0[1], q0z = s_q0[2];

    while (bcount > CAND_CAP && shift > 0) {
        int newshift = (shift > 11) ? (shift - 11) : 0;
        unsigned digmask = (1u << (shift - newshift)) - 1;
        for (int i = tid; i < NHIST; i += BLOCK) hist[i] = 0;
        __syncthreads();
        for (int j = tid; j < nfus; j += BLOCK) {
            unsigned k = key_of(fus, j, vx, vy, vz);
            if ((k >> shift) == T) atomicAdd(&hist[(k >> newshift) & digmask], 1u);
        }
        __syncthreads();
        find_bucket_dev<BLOCK>(hist, rem, waveTot, waveBase, &s_bucket, &s_rem, &s_bcount, tid);
        T = (T << (shift - newshift)) | s_bucket;
        rem = s_rem;
        bcount = s_bcount;
        shift = newshift;
    }

    if (fastOK && shift == 21) {
        for (int i = tid; i < cnRaw; i += BLOCK) {
            unsigned long long p = clist[i];
            unsigned hi = (unsigned)(p >> 53);
            if (hi < T) {
                int pos = atomicAdd(&s_wcount, 1);
                if (pos < WCAP) wlist[pos] = (int)(p & 0xFFFFFFFFull);
            } else if (hi == T) {
                int pos = atomicAdd(&s_candCount, 1);
                if (pos < CAND_CAP) cand[pos] = p;
            }
        }
    } else {
        for (int j = tid; j < nfus; j += BLOCK) {
            unsigned k = key_of(fus, j, vx, vy, vz);
            unsigned hi = k >> shift;
            if (hi < T) { int pos = atomicAdd(&s_wcount, 1); if (pos < WCAP) wlist[pos] = j; }
            else if (hi == T) { int pos = atomicAdd(&s_candCount, 1); if (pos < CAND_CAP) cand[pos] = ((unsigned long long)k << 32) | (unsigned)j; }
        }
    }
    __syncthreads();

    const int cnt = s_candCount;
    if (cnt <= CAND_CAP) {
        for (int i = tid; i < cnt; i += BLOCK) {
            unsigned long long me = cand[i];
            int rank = 0;
            for (int k2i = 0; k2i < cnt; k2i++) rank += (cand[k2i] < me) ? 1 : 0;
            if (rank < (int)rem) {
                int pos = atomicAdd(&s_wcount, 1);
                if (pos < WCAP) wlist[pos] = (int)(me & 0xFFFFFFFFull);
            }
        }
    }
    __syncthreads();

    {
        int wc = s_wcount; if (wc > WCAP) wc = WCAP;
        for (int i = tid; i < wc; i += BLOCK) {
            int j = wlist[i];
            float fxs = fus[3 * j], fys = fus[3 * j + 1], fzs = fus[3 * j + 2];
            int bin = compute_bin(__fsub_rn(fxs, q0x), __fsub_rn(fys, q0y), __fsub_rn(fzs, q0z));
            if (bin >= 0 && bin < NPART) atomicAdd(&hist32[bin], 1u);
        }
    }
    __syncthreads();

    if (cnt > CAND_CAP) {
        if (tid == 0) s_lowBound = 0;
        __syncthreads();
        for (unsigned itx = 0; itx < rem; ++itx) {
            if (tid == 0) s_minPacked = ~0ull;
            __syncthreads();
            unsigned long long lowB = s_lowBound;
            unsigned long long lm = ~0ull;
            for (int j = tid; j < nfus; j += BLOCK) {
                unsigned k = key_of(fus, j, vx, vy, vz);
                if ((k >> shift) == T) {
                    unsigned long long p = ((unsigned long long)k << 32) | (unsigned)j;
                    if (p >= lowB && p < lm) lm = p;
                }
            }
            #pragma unroll
            for (int d = 32; d > 0; d >>= 1) {
                unsigned long long o = __shfl_xor(lm, d, 64);
                lm = (o < lm) ? o : lm;
            }
            if (lane == 0) atomicMin(&s_minPacked, lm);
            __syncthreads();
            if (tid == 0) {
                int jm = (int)(s_minPacked & 0xFFFFFFFFull);
                float fxs = fus[jm * 3], fys = fus[jm * 3 + 1], fzs = fus[jm * 3 + 2];
                int bin = compute_bin(__fsub_rn(fxs, q0x), __fsub_rn(fys, q0y), __fsub_rn(fzs, q0z));
                if (bin >= 0 && bin < NPART) hist32[bin] += 1u;
                s_lowBound = s_minPacked + 1;
            }
            __syncthreads();
        }
    }

    if (tid < NPART) {
        float c = (float)hist32[tid] + 1.0f;
        float ss = __fmul_rn(c, c);
        #pragma unroll
        for (int d = 16; d > 0; d >>= 1) ss += __shfl_xor(ss, d, 64);
        float v = __fmul_rn(__fdiv_rn(c, sqrtf(ss)), 4.0f);
        float mx = v;
        #pragma unroll
        for (int d = 16; d > 0; d >>= 1) mx = fmaxf(mx, __shfl_xor(mx, d, 64));
        float e = expf(v - mx);
        float sum = e;
        #pragma unroll
        for (int d = 16; d > 0; d >>= 1) sum += __shfl_xor(sum, d, 64);
        out[b * NPART + tid] = __fdiv_rn(e, sum);
    }
}

extern "C" void kernel_launch(void* const* d_in, const int* in_sizes, int n_in,
                              void* d_out, int out_size, void* d_ws, size_t ws_size,
                              hipStream_t stream) {
    const float* veh = (const float*)d_in[0];   // (1024, 3)
    const float* fus = (const float*)d_in[1];   // (20000, 3)
    float* out = (float*)d_out;                 // (1024, 32)
    int nveh = in_sizes[0] / 3;
    int nfus = in_sizes[1] / 3;

    // workspace layout: fx | fy | fz | maxKey[nveh] | count[nveh] | clist[nveh][CLIST_CAP]
    size_t nf4   = (size_t)((nfus + 3) >> 2);
    size_t PB    = ((nf4 * 16) + 255) & ~(size_t)255;
    size_t szA   = (((size_t)nveh * 4) + 255) & ~(size_t)255;
    size_t offMk = 3 * PB;
    size_t offCnt = offMk + szA;
    size_t offCl  = offCnt + szA;
    size_t need   = offCl + (size_t)nveh * CLIST_CAP * 8;

    if (d_ws == nullptr || ws_size < need) {
        shape_context_mono<<<nveh, BLOCK, 0, stream>>>(veh, fus, out, nfus);
        return;
    }

    char* ws = (char*)d_ws;
    float* fx = (float*)(ws);
    float* fy = (float*)(ws + PB);
    float* fz = (float*)(ws + 2 * PB);
    unsigned* mk = (unsigned*)(ws + offMk);
    int* cnt = (int*)(ws + offCnt);
    unsigned long long* cl = (unsigned long long*)(ws + offCl);

    int padN = (int)nf4 * 4;
    int g0 = (padN + 255) / 256;
    planarize_kernel<<<g0, 256, 0, stream>>>(fus, fx, fy, fz, nfus, padN);
    sample_bound_kernel<<<nveh, K0B, 0, stream>>>(veh, fx, fy, fz, mk, cnt, nfus);
    int ppc = ((nfus + NCHUNK - 1) / NCHUNK + 3) & ~3;
    stream_filter_kernel<<<nveh * NCHUNK, K1B, 0, stream>>>(
        veh, (const float4*)fx, (const float4*)fy, (const float4*)fz, mk, cnt, cl, nfus, ppc);
    select_bin_kernel<<<nveh, K2B, 0, stream>>>(veh, fx, fy, fz, mk, cnt, cl, out, nfus);
}

// Round 7
// 79.187 us; speedup vs baseline: 2.0057x; 2.0057x over previous
//
#include <hip/hip_runtime.h>
#include <math.h>

#define KTOP 200
#define NPART 32
#define BLOCK 512
#define NHIST 2048
#define CAND_CAP 512
#define WCAP 512
#define CLIST_CAP 1536   // expected qualifying keys ~650 (srank=64 * nfus/sample); big margin
#define SRANK_MIN 64u    // sample rank for bound E; 64 => ~17 sigma margin

// d2 exactly as numpy: ((dx*dx + dy*dy) + dz*dz), no fma contraction
__device__ __forceinline__ float d2_ref(float ax, float ay, float az,
                                        float bx, float by, float bz) {
    float dx = __fsub_rn(ax, bx), dy = __fsub_rn(ay, by), dz = __fsub_rn(az, bz);
    return __fadd_rn(__fadd_rn(__fmul_rn(dx, dx), __fmul_rn(dy, dy)), __fmul_rn(dz, dz));
}

__device__ __forceinline__ unsigned key2(float cx, float cy, float cz,
                                         float px, float py, float pz) {
    return __float_as_uint(d2_ref(cx, cy, cz, px, py, pz));
}

__device__ __forceinline__ unsigned key_of(const float* __restrict__ fus, int j,
                                           float vx, float vy, float vz) {
    return __float_as_uint(d2_ref(vx, vy, vz, fus[3*j], fus[3*j+1], fus[3*j+2]));
}

// shape-context bin of rel = p_j - q0, mirroring the reference f32 math
__device__ __forceinline__ int compute_bin(float rx, float ry, float rz) {
    const float TWO_PI_F = (float)6.283185307179586;
    const float PI_F     = (float)3.141592653589793;
    const float XY_W     = (float)(6.283185307179586 / 4.0);
    const float ZY_W     = (float)(3.141592653589793 / 4.0);

    float d2 = __fadd_rn(__fadd_rn(__fmul_rn(rx, rx), __fmul_rn(ry, ry)), __fmul_rn(rz, rz));
    float D  = sqrtf(__fadd_rn(d2, 1e-7f));
    float dist_bin;
    if (D >= 4.0f)      dist_bin = 1.0f;
    else if (D >= 1.0f) dist_bin = 0.0f;
    else                return -1;

    float axy = fmodf(atan2f(ry, rx) + TWO_PI_F, TWO_PI_F);
    float azy = fmodf(atan2f(ry, rz) + TWO_PI_F, PI_F);
    float xyb = floorf(__fdiv_rn(axy, XY_W));
    float zyb = floorf(__fdiv_rn(azy, ZY_W));
    if (!(xyb >= 0.0f && zyb >= 0.0f)) return -1;
    float ab  = xyb * 4.0f + zyb;
    int bin = (int)(dist_bin * 16.0f + ab);
    return bin;
}

// ---- AoS (20000,3) -> 3 planes. Reads coalesced; writes near-coalesced (stride-1/3). ----
__global__ void planarize_kernel(const float* __restrict__ fus,
                                 float* __restrict__ fx, float* __restrict__ fy,
                                 float* __restrict__ fz, int nfus) {
    const int n3 = 3 * nfus;
    for (int t = blockIdx.x * blockDim.x + threadIdx.x; t < n3; t += gridDim.x * blockDim.x) {
        float val = fus[t];
        int p = t / 3;             // compiler magic-div
        int d = t - 3 * p;
        float* dst = (d == 0) ? fx : ((d == 1) ? fy : fz);
        dst[p] = val;
    }
}

// PLANAR=true: all bulk loads unit-stride from fx/fy/fz planes. PLANAR=false: r5 AoS path.
template<bool PLANAR>
__global__ __launch_bounds__(BLOCK, 8)
void shape_context_kernel(const float* __restrict__ veh,
                          const float* __restrict__ fus,
                          const float* __restrict__ fxp,
                          const float* __restrict__ fyp,
                          const float* __restrict__ fzp,
                          float* __restrict__ out,
                          int nfus) {
    const int b   = blockIdx.x;
    const int tid = threadIdx.x;
    const int lane = tid & 63;
    const int wid  = tid >> 6;

    __shared__ unsigned int hist[NHIST];
    __shared__ unsigned long long clist[CLIST_CAP];  // packed (key<<32 | idx), keys with bucket <= E
    __shared__ unsigned long long cand[CAND_CAP];
    __shared__ int wlist[WCAP];
    __shared__ unsigned int hist32[NPART];
    __shared__ unsigned int waveTot[BLOCK / 64];
    __shared__ unsigned int waveBase[BLOCK / 64];
    __shared__ unsigned int s_bucket, s_rem, s_bcount;
    __shared__ int s_candCount, s_wcount, s_clistCount;
    __shared__ float s_q0[3];
    __shared__ unsigned long long s_minPacked, s_lowBound;

    const float vx = veh[b * 3 + 0], vy = veh[b * 3 + 1], vz = veh[b * 3 + 2];
    const float4* fus4 = (const float4*)fus;
    const float4* fx4 = (const float4*)fxp;
    const float4* fy4 = (const float4*)fyp;
    const float4* fz4 = (const float4*)fzp;
    const int ntrip = nfus >> 2;

    if (tid == 0) { s_minPacked = ~0ull; s_candCount = 0; s_wcount = 0; s_clistCount = 0; }
    for (int i = tid; i < NHIST; i += BLOCK) hist[i] = 0;
    if (tid < NPART) hist32[tid] = 0;
    __syncthreads();

    // parallel "find bucket where cumulative count crosses remq" over hist[NHIST]
    // leaves s_bucket = 0xFFFFFFFF if the cumulative never reaches remq
    auto find_bucket = [&](unsigned remq) {
        if (tid == 0) s_bucket = 0xFFFFFFFFu;
        const int PER = NHIST / BLOCK;  // 4
        int base = tid * PER;
        unsigned p = 0;
        #pragma unroll
        for (int i = 0; i < PER; i++) p += hist[base + i];
        unsigned incl = p;
        #pragma unroll
        for (int d = 1; d < 64; d <<= 1) {
            unsigned n = __shfl_up(incl, d, 64);
            if (lane >= d) incl += n;
        }
        if (lane == 63) waveTot[wid] = incl;
        __syncthreads();
        if (tid == 0) {
            unsigned acc = 0;
            for (int w = 0; w < BLOCK / 64; w++) { waveBase[w] = acc; acc += waveTot[w]; }
        }
        __syncthreads();
        unsigned excl = waveBase[wid] + incl - p;
        if (excl < remq && remq <= excl + p) {
            unsigned cum = excl;
            #pragma unroll
            for (int i = 0; i < PER; i++) {
                unsigned c = hist[base + i];
                if (cum + c >= remq) { s_bucket = base + i; s_rem = remq - cum; s_bcount = c; break; }
                cum += c;
            }
        }
        __syncthreads();
    };

    // per-lane push (sample/tail only; stream uses wave-aggregated path)
    auto push_l = [&](unsigned k, unsigned j) {
        int pos = atomicAdd(&s_clistCount, 1);
        if (pos < CLIST_CAP) clist[pos] = ((unsigned long long)k << 32) | j;
    };

    // key of point j via planes (coalesced when j is stride-BLOCK) or AoS
    auto key_j = [&](int j) {
        if constexpr (PLANAR) return key2(vx, vy, vz, fxp[j], fyp[j], fzp[j]);
        else                  return key_of(fus, j, vx, vy, vz);
    };

    // ---- trip 0: full histogram of the first 4*BLOCK points (i.i.d. random sample) ----
    unsigned k0 = 0, k1 = 0, k2 = 0, k3 = 0;
    const bool t0v = (tid < ntrip);
    if (t0v) {
        if constexpr (PLANAR) {
            float4 X = fx4[tid], Y = fy4[tid], Z = fz4[tid];
            k0 = key2(vx, vy, vz, X.x, Y.x, Z.x);
            k1 = key2(vx, vy, vz, X.y, Y.y, Z.y);
            k2 = key2(vx, vy, vz, X.z, Y.z, Z.z);
            k3 = key2(vx, vy, vz, X.w, Y.w, Z.w);
        } else {
            float4 A = fus4[3 * tid], Bq = fus4[3 * tid + 1], Cq = fus4[3 * tid + 2];
            k0 = key2(vx, vy, vz, A.x,  A.y,  A.z);
            k1 = key2(vx, vy, vz, A.w,  Bq.x, Bq.y);
            k2 = key2(vx, vy, vz, Bq.z, Bq.w, Cq.x);
            k3 = key2(vx, vy, vz, Cq.y, Cq.z, Cq.w);
        }
        atomicAdd(&hist[k0 >> 21], 1u);
        atomicAdd(&hist[k1 >> 21], 1u);
        atomicAdd(&hist[k2 >> 21], 1u);
        atomicAdd(&hist[k3 >> 21], 1u);
    }
    __syncthreads();

    // ---- E: conservative upper-bound bucket for the KTOP-th key, from the sample ----
    unsigned srank;
    {
        long long sample = (long long)((ntrip < BLOCK) ? ntrip : BLOCK) * 4;
        if (sample >= (long long)nfus) {
            srank = KTOP;  // sample is the whole population -> exact
        } else {
            unsigned s2 = (unsigned)(((long long)3 * KTOP * sample + nfus - 1) / nfus);
            srank = (s2 < SRANK_MIN) ? SRANK_MIN : s2;
        }
    }
    find_bucket(srank);
    const unsigned E = (s_bucket < NHIST) ? s_bucket : (NHIST - 1);  // unset -> no filtering
    // all keys <= maxKey lie in buckets <= E (positive-float bit order == value order)
    const unsigned maxKey = ((E + 1u) << 21) - 1u;

    // sample keys: push qualifiers into clist (hist on [0,E] is rebuilt from clist later)
    if (t0v) {
        unsigned jb = 4u * (unsigned)tid;
        if (k0 <= maxKey) push_l(k0, jb + 0);
        if (k1 <= maxKey) push_l(k1, jb + 1);
        if (k2 <= maxKey) push_l(k2, jb + 2);
        if (k3 <= maxKey) push_l(k3, jb + 3);
    }

    // ---- main stream: 1 uint compare per key; wave-aggregated push; coalesced plane loads ----
    {
        int m = BLOCK + tid;
        bool valid = (m < ntrip);
        float4 A, Bq, Cq;   // PLANAR: X,Y,Z planes; AoS: packed triplets
        if (valid) {
            if constexpr (PLANAR) { A = fx4[m]; Bq = fy4[m]; Cq = fz4[m]; }
            else                  { A = fus4[3 * m]; Bq = fus4[3 * m + 1]; Cq = fus4[3 * m + 2]; }
        }
        while (valid) {
            const int mn = m + BLOCK;
            const bool vnext = (mn < ntrip);
            float4 An, Bn, Cn;
            if (vnext) {
                if constexpr (PLANAR) { An = fx4[mn]; Bn = fy4[mn]; Cn = fz4[mn]; }
                else                  { An = fus4[3 * mn]; Bn = fus4[3 * mn + 1]; Cn = fus4[3 * mn + 2]; }
            }

            unsigned q0k, q1k, q2k, q3k;
            if constexpr (PLANAR) {
                q0k = key2(vx, vy, vz, A.x, Bq.x, Cq.x);
                q1k = key2(vx, vy, vz, A.y, Bq.y, Cq.y);
                q2k = key2(vx, vy, vz, A.z, Bq.z, Cq.z);
                q3k = key2(vx, vy, vz, A.w, Bq.w, Cq.w);
            } else {
                q0k = key2(vx, vy, vz, A.x,  A.y,  A.z);
                q1k = key2(vx, vy, vz, A.w,  Bq.x, Bq.y);
                q2k = key2(vx, vy, vz, Bq.z, Bq.w, Cq.x);
                q3k = key2(vx, vy, vz, Cq.y, Cq.z, Cq.w);
            }
            // loop-exit drops HIGH lanes first (m grows with lane) => lane 0 active
            // whenever any lane is, so the lane-0 atomic below is safe.
            unsigned long long m0 = __ballot(q0k <= maxKey);
            unsigned long long m1 = __ballot(q1k <= maxKey);
            unsigned long long m2 = __ballot(q2k <= maxKey);
            unsigned long long m3 = __ballot(q3k <= maxKey);
            if (m0 | m1 | m2 | m3) {             // wave-uniform branch
                int c0 = __popcll(m0), c1 = __popcll(m1), c2 = __popcll(m2);
                int tot = c0 + c1 + c2 + __popcll(m3);
                int base = 0;
                if (lane == 0) base = atomicAdd(&s_clistCount, tot);
                base = __shfl(base, 0, 64);
                const unsigned long long lt = (1ull << lane) - 1ull;
                unsigned jb = 4u * (unsigned)m;
                int o0 = base + (int)__popcll(m0 & lt);
                int o1 = base + c0 + (int)__popcll(m1 & lt);
                int o2 = base + c0 + c1 + (int)__popcll(m2 & lt);
                int o3 = base + c0 + c1 + c2 + (int)__popcll(m3 & lt);
                if (q0k <= maxKey && o0 < CLIST_CAP) clist[o0] = ((unsigned long long)q0k << 32) | (jb + 0);
                if (q1k <= maxKey && o1 < CLIST_CAP) clist[o1] = ((unsigned long long)q1k << 32) | (jb + 1);
                if (q2k <= maxKey && o2 < CLIST_CAP) clist[o2] = ((unsigned long long)q2k << 32) | (jb + 2);
                if (q3k <= maxKey && o3 < CLIST_CAP) clist[o3] = ((unsigned long long)q3k << 32) | (jb + 3);
            }
            A = An; Bq = Bn; Cq = Cn; m = mn; valid = vnext;
        }
    }
    // tail (nfus % 4): at most 3 points, per-lane push
    for (int j = (nfus & ~3) + tid; j < nfus; j += BLOCK) {
        unsigned k = key_j(j);
        if (k <= maxKey) push_l(k, (unsigned)j);
    }
    __syncthreads();

    // ---- rebuild exact hist on [0, E] from clist (no overflow => clist is the exact
    //      multiset of keys with bucket <= E, sample included) ----
    const int cnRaw = s_clistCount;
    const bool noOvf = (cnRaw <= CLIST_CAP);
    if (noOvf) {
        for (int i = tid; i <= (int)E; i += BLOCK) hist[i] = 0;
        __syncthreads();
        for (int i = tid; i < cnRaw; i += BLOCK)
            atomicAdd(&hist[(unsigned)(clist[i] >> 53)], 1u);
        __syncthreads();
    }

    // hist exact on [0, E]; garbage (sample-only) above E. A crossing at T <= E is exact.
    find_bucket(KTOP);
    unsigned T = s_bucket;
    unsigned rem = s_rem;
    unsigned bcount = s_bcount;
    int shift = 21;
    const bool fastOK = noOvf && (T <= E);

    if (fastOK) {
        // argmin (= top-1, always bucket <= E, always in clist) from the compact list
        unsigned long long lm = ~0ull;
        for (int i = tid; i < cnRaw; i += BLOCK) { unsigned long long p = clist[i]; lm = (p < lm) ? p : lm; }
        #pragma unroll
        for (int d = 32; d > 0; d >>= 1) {
            unsigned long long o = __shfl_xor(lm, d, 64);
            lm = (o < lm) ? o : lm;
        }
        if (lane == 0) atomicMin(&s_minPacked, lm);
        __syncthreads();
    } else {
        // rare: bound E failed or clist overflowed -> rebuild full exact histogram + argmin
        for (int i = tid; i < NHIST; i += BLOCK) hist[i] = 0;
        __syncthreads();
        unsigned long long lm = ~0ull;
        for (int j = tid; j < nfus; j += BLOCK) {
            unsigned k = key_j(j);
            atomicAdd(&hist[k >> 21], 1u);
            unsigned long long p = ((unsigned long long)k << 32) | (unsigned)j;
            lm = (p < lm) ? p : lm;
        }
        #pragma unroll
        for (int d = 32; d > 0; d >>= 1) {
            unsigned long long o = __shfl_xor(lm, d, 64);
            lm = (o < lm) ? o : lm;
        }
        if (lane == 0) atomicMin(&s_minPacked, lm);
        __syncthreads();
        find_bucket(KTOP);
        T = s_bucket; rem = s_rem; bcount = s_bcount;
    }

    if (tid == 0) {
        int idx0 = (int)(s_minPacked & 0xFFFFFFFFull);
        if constexpr (PLANAR) { s_q0[0] = fxp[idx0]; s_q0[1] = fyp[idx0]; s_q0[2] = fzp[idx0]; }
        else { s_q0[0] = fus[idx0 * 3]; s_q0[1] = fus[idx0 * 3 + 1]; s_q0[2] = fus[idx0 * 3 + 2]; }
    }
    __syncthreads();
    const float q0x = s_q0[0], q0y = s_q0[1], q0z = s_q0[2];

    // ---- rare: refine threshold bucket if too many candidates (reload-based) ----
    while (bcount > CAND_CAP && shift > 0) {
        int newshift = (shift > 11) ? (shift - 11) : 0;
        unsigned digmask = (1u << (shift - newshift)) - 1;
        for (int i = tid; i < NHIST; i += BLOCK) hist[i] = 0;
        __syncthreads();
        for (int j = tid; j < nfus; j += BLOCK) {
            unsigned k = key_j(j);
            if ((k >> shift) == T) atomicAdd(&hist[(k >> newshift) & digmask], 1u);
        }
        __syncthreads();
        find_bucket(rem);
        T = (T << (shift - newshift)) | s_bucket;
        rem = s_rem;
        bcount = s_bcount;
        shift = newshift;
    }

    // ---- scan B: winners -> wlist, boundary bucket -> cand ----
    if (fastOK && shift == 21) {
        // walk the compact candidate list (exact packed keys, ~650 entries)
        for (int i = tid; i < cnRaw; i += BLOCK) {
            unsigned long long p = clist[i];
            unsigned hi = (unsigned)(p >> 53);   // == key >> 21
            if (hi < T) {
                int pos = atomicAdd(&s_wcount, 1);
                if (pos < WCAP) wlist[pos] = (int)(p & 0xFFFFFFFFull);
            } else if (hi == T) {
                int pos = atomicAdd(&s_candCount, 1);
                if (pos < CAND_CAP) cand[pos] = p;
            }
        }
    } else {
        for (int j = tid; j < nfus; j += BLOCK) {
            unsigned k = key_j(j);
            unsigned hi = k >> shift;
            if (hi < T) { int pos = atomicAdd(&s_wcount, 1); if (pos < WCAP) wlist[pos] = j; }
            else if (hi == T) { int pos = atomicAdd(&s_candCount, 1); if (pos < CAND_CAP) cand[pos] = ((unsigned long long)k << 32) | (unsigned)j; }
        }
    }
    __syncthreads();

    const int cnt = s_candCount;
    if (cnt <= CAND_CAP) {
        // exact stable ranking among boundary candidates by (key, idx); qualifiers join wlist
        for (int i = tid; i < cnt; i += BLOCK) {
            unsigned long long me = cand[i];
            int rank = 0;
            for (int k2i = 0; k2i < cnt; k2i++) rank += (cand[k2i] < me) ? 1 : 0;
            if (rank < (int)rem) {
                int pos = atomicAdd(&s_wcount, 1);
                if (pos < WCAP) wlist[pos] = (int)(me & 0xFFFFFFFFull);
            }
        }
    }
    __syncthreads();

    // ---- compact winner processing: ~one compute_bin per thread ----
    {
        int wc = s_wcount; if (wc > WCAP) wc = WCAP;
        for (int i = tid; i < wc; i += BLOCK) {
            int j = wlist[i];
            float fxs, fys, fzs;
            if constexpr (PLANAR) { fxs = fxp[j]; fys = fyp[j]; fzs = fzp[j]; }
            else { fxs = fus[3 * j]; fys = fus[3 * j + 1]; fzs = fus[3 * j + 2]; }
            int bin = compute_bin(__fsub_rn(fxs, q0x), __fsub_rn(fys, q0y), __fsub_rn(fzs, q0z));
            if (bin >= 0 && bin < NPART) atomicAdd(&hist32[bin], 1u);
        }
    }
    __syncthreads();

    if (cnt > CAND_CAP) {
        // pathological fallback: serial extraction of `rem` smallest packed (key,idx) in bucket T
        if (tid == 0) s_lowBound = 0;
        __syncthreads();
        for (unsigned itx = 0; itx < rem; ++itx) {
            if (tid == 0) s_minPacked = ~0ull;
            __syncthreads();
            unsigned long long lowB = s_lowBound;
            unsigned long long lm = ~0ull;
            for (int j = tid; j < nfus; j += BLOCK) {
                unsigned k = key_j(j);
                if ((k >> shift) == T) {
                    unsigned long long p = ((unsigned long long)k << 32) | (unsigned)j;
                    if (p >= lowB && p < lm) lm = p;
                }
            }
            #pragma unroll
            for (int d = 32; d > 0; d >>= 1) {
                unsigned long long o = __shfl_xor(lm, d, 64);
                lm = (o < lm) ? o : lm;
            }
            if (lane == 0) atomicMin(&s_minPacked, lm);
            __syncthreads();
            if (tid == 0) {
                int jm = (int)(s_minPacked & 0xFFFFFFFFull);
                float fxs, fys, fzs;
                if constexpr (PLANAR) { fxs = fxp[jm]; fys = fyp[jm]; fzs = fzp[jm]; }
                else { fxs = fus[3 * jm]; fys = fus[3 * jm + 1]; fzs = fus[3 * jm + 2]; }
                int bin = compute_bin(__fsub_rn(fxs, q0x), __fsub_rn(fys, q0y), __fsub_rn(fzs, q0z));
                if (bin >= 0 && bin < NPART) hist32[bin] += 1u;
                s_lowBound = s_minPacked + 1;
            }
            __syncthreads();
        }
    }

    // ---- epilogue (32 lanes of wave 0): counts+1 -> L2-normalize*4 -> softmax ----
    if (tid < NPART) {
        float c = (float)hist32[tid] + 1.0f;
        float ss = __fmul_rn(c, c);
        #pragma unroll
        for (int d = 16; d > 0; d >>= 1) ss += __shfl_xor(ss, d, 64);
        float v = __fmul_rn(__fdiv_rn(c, sqrtf(ss)), 4.0f);
        float mx = v;
        #pragma unroll
        for (int d = 16; d > 0; d >>= 1) mx = fmaxf(mx, __shfl_xor(mx, d, 64));
        float e = expf(v - mx);
        float sum = e;
        #pragma unroll
        for (int d = 16; d > 0; d >>= 1) sum += __shfl_xor(sum, d, 64);
        out[b * NPART + tid] = __fdiv_rn(e, sum);
    }
}

extern "C" void kernel_launch(void* const* d_in, const int* in_sizes, int n_in,
                              void* d_out, int out_size, void* d_ws, size_t ws_size,
                              hipStream_t stream) {
    const float* veh = (const float*)d_in[0];   // (1024, 3)
    const float* fus = (const float*)d_in[1];   // (20000, 3)
    float* out = (float*)d_out;                 // (1024, 32)
    int nveh = in_sizes[0] / 3;
    int nfus = in_sizes[1] / 3;

    // workspace: 3 float4-padded planes fx | fy | fz
    size_t nf4 = (size_t)((nfus + 3) >> 2);
    size_t PB  = ((nf4 * 16) + 255) & ~(size_t)255;   // bytes per plane, 256-aligned
    size_t need = 3 * PB;

    if (d_ws != nullptr && ws_size >= need) {
        char* ws = (char*)d_ws;
        float* fx = (float*)(ws);
        float* fy = (float*)(ws + PB);
        float* fz = (float*)(ws + 2 * PB);
        int g0 = (3 * nfus + 255) / 256;
        planarize_kernel<<<g0, 256, 0, stream>>>(fus, fx, fy, fz, nfus);
        shape_context_kernel<true><<<nveh, BLOCK, 0, stream>>>(veh, fus, fx, fy, fz, out, nfus);
    } else {
        shape_context_kernel<false><<<nveh, BLOCK, 0, stream>>>(
            veh, fus, nullptr, nullptr, nullptr, out, nfus);
    }
}

// Round 8
// 76.549 us; speedup vs baseline: 2.0748x; 1.0345x over previous
//
#include <hip/hip_runtime.h>
#include <math.h>

#define KTOP 200
#define NPART 32
#define BLOCK 512
#define NHIST 2048
#define CAND_CAP 512
#define WCAP 512
#define CLIST_CAP 1536   // expected qualifying keys ~650 (srank=64 * nfus/sample); big margin
#define SRANK_MIN 64u    // sample rank for bound E; 64 => ~17 sigma margin

// d2 exactly as numpy: ((dx*dx + dy*dy) + dz*dz), no fma contraction
__device__ __forceinline__ float d2_ref(float ax, float ay, float az,
                                        float bx, float by, float bz) {
    float dx = __fsub_rn(ax, bx), dy = __fsub_rn(ay, by), dz = __fsub_rn(az, bz);
    return __fadd_rn(__fadd_rn(__fmul_rn(dx, dx), __fmul_rn(dy, dy)), __fmul_rn(dz, dz));
}

__device__ __forceinline__ unsigned key_of(const float* __restrict__ fus, int j,
                                           float vx, float vy, float vz) {
    return __float_as_uint(d2_ref(vx, vy, vz, fus[3*j], fus[3*j+1], fus[3*j+2]));
}

// shape-context bin of rel = p_j - q0, mirroring the reference f32 math
__device__ __forceinline__ int compute_bin(float rx, float ry, float rz) {
    const float TWO_PI_F = (float)6.283185307179586;
    const float PI_F     = (float)3.141592653589793;
    const float XY_W     = (float)(6.283185307179586 / 4.0);
    const float ZY_W     = (float)(3.141592653589793 / 4.0);

    float d2 = __fadd_rn(__fadd_rn(__fmul_rn(rx, rx), __fmul_rn(ry, ry)), __fmul_rn(rz, rz));
    float D  = sqrtf(__fadd_rn(d2, 1e-7f));
    float dist_bin;
    if (D >= 4.0f)      dist_bin = 1.0f;
    else if (D >= 1.0f) dist_bin = 0.0f;
    else                return -1;

    float axy = fmodf(atan2f(ry, rx) + TWO_PI_F, TWO_PI_F);
    float azy = fmodf(atan2f(ry, rz) + TWO_PI_F, PI_F);
    float xyb = floorf(__fdiv_rn(axy, XY_W));
    float zyb = floorf(__fdiv_rn(azy, ZY_W));
    if (!(xyb >= 0.0f && zyb >= 0.0f)) return -1;
    float ab  = xyb * 4.0f + zyb;
    int bin = (int)(dist_bin * 16.0f + ab);
    return bin;
}

__global__ __launch_bounds__(BLOCK, 8)
void shape_context_kernel(const float* __restrict__ veh,
                          const float* __restrict__ fus,
                          float* __restrict__ out,
                          int nfus) {
    const int b   = blockIdx.x;
    const int tid = threadIdx.x;
    const int lane = tid & 63;
    const int wid  = tid >> 6;
    const int bank = wid & 1;

    // dual-bank histogram: waves split by parity -> halves same-address atomic serialization
    __shared__ unsigned int hist2[2][NHIST];         // 16 KB
    __shared__ unsigned long long clist[CLIST_CAP];  // 12 KB; packed (key<<32 | idx), bucket <= E
    __shared__ unsigned long long cand[CAND_CAP];    // 4 KB
    __shared__ int wlist[WCAP];                      // 2 KB
    __shared__ unsigned int hist32[NPART];
    __shared__ unsigned int waveTot[BLOCK / 64];
    __shared__ unsigned int waveBase[BLOCK / 64];
    __shared__ unsigned int s_bucket, s_rem, s_bcount;
    __shared__ int s_candCount, s_wcount, s_clistCount;
    __shared__ float s_q0[3];
    __shared__ unsigned long long s_minPacked, s_lowBound;

    const float vx = veh[b * 3 + 0], vy = veh[b * 3 + 1], vz = veh[b * 3 + 2];
    const float4* fus4 = (const float4*)fus;
    const int ntrip = nfus >> 2;

    if (tid == 0) { s_minPacked = ~0ull; s_candCount = 0; s_wcount = 0; s_clistCount = 0; }
    for (int i = tid; i < NHIST; i += BLOCK) { hist2[0][i] = 0; hist2[1][i] = 0; }
    if (tid < NPART) hist32[tid] = 0;
    __syncthreads();

    // parallel "find bucket where cumulative (bank0+bank1) crosses remq"
    // leaves s_bucket = 0xFFFFFFFF if the cumulative never reaches remq
    auto find_bucket = [&](unsigned remq) {
        if (tid == 0) s_bucket = 0xFFFFFFFFu;
        const int PER = NHIST / BLOCK;  // 4
        int base = tid * PER;
        unsigned p = 0;
        #pragma unroll
        for (int i = 0; i < PER; i++) p += hist2[0][base + i] + hist2[1][base + i];
        unsigned incl = p;
        #pragma unroll
        for (int d = 1; d < 64; d <<= 1) {
            unsigned n = __shfl_up(incl, d, 64);
            if (lane >= d) incl += n;
        }
        if (lane == 63) waveTot[wid] = incl;
        __syncthreads();
        if (tid == 0) {
            unsigned acc = 0;
            for (int w = 0; w < BLOCK / 64; w++) { waveBase[w] = acc; acc += waveTot[w]; }
        }
        __syncthreads();
        unsigned excl = waveBase[wid] + incl - p;
        if (excl < remq && remq <= excl + p) {
            unsigned cum = excl;
            #pragma unroll
            for (int i = 0; i < PER; i++) {
                unsigned c = hist2[0][base + i] + hist2[1][base + i];
                if (cum + c >= remq) { s_bucket = base + i; s_rem = remq - cum; s_bcount = c; break; }
                cum += c;
            }
        }
        __syncthreads();
    };

    // per-lane push (tail only; bulk paths use wave-aggregated push)
    auto push_l = [&](unsigned k, unsigned j) {
        int pos = atomicAdd(&s_clistCount, 1);
        if (pos < CLIST_CAP) clist[pos] = ((unsigned long long)k << 32) | j;
    };

    // wave-aggregated push of up to 4 qualifying keys. Caller guarantees lane 0 of the
    // wave is active whenever any lane is (high lanes drop out first in all call sites).
    auto agg_push4 = [&](unsigned q0k, unsigned q1k, unsigned q2k, unsigned q3k,
                         unsigned maxKey, unsigned jb) {
        unsigned long long m0 = __ballot(q0k <= maxKey);
        unsigned long long m1 = __ballot(q1k <= maxKey);
        unsigned long long m2 = __ballot(q2k <= maxKey);
        unsigned long long m3 = __ballot(q3k <= maxKey);
        if (m0 | m1 | m2 | m3) {             // wave-uniform branch
            int c0 = __popcll(m0), c1 = __popcll(m1), c2 = __popcll(m2);
            int tot = c0 + c1 + c2 + __popcll(m3);
            int base = 0;
            if (lane == 0) base = atomicAdd(&s_clistCount, tot);
            base = __shfl(base, 0, 64);
            const unsigned long long lt = (1ull << lane) - 1ull;
            int o0 = base + (int)__popcll(m0 & lt);
            int o1 = base + c0 + (int)__popcll(m1 & lt);
            int o2 = base + c0 + c1 + (int)__popcll(m2 & lt);
            int o3 = base + c0 + c1 + c2 + (int)__popcll(m3 & lt);
            if (q0k <= maxKey && o0 < CLIST_CAP) clist[o0] = ((unsigned long long)q0k << 32) | (jb + 0);
            if (q1k <= maxKey && o1 < CLIST_CAP) clist[o1] = ((unsigned long long)q1k << 32) | (jb + 1);
            if (q2k <= maxKey && o2 < CLIST_CAP) clist[o2] = ((unsigned long long)q2k << 32) | (jb + 2);
            if (q3k <= maxKey && o3 < CLIST_CAP) clist[o3] = ((unsigned long long)q3k << 32) | (jb + 3);
        }
    };

    // ---- trip 0: full histogram of the first 4*BLOCK points (i.i.d. random sample) ----
    unsigned k0 = 0, k1 = 0, k2 = 0, k3 = 0;
    const bool t0v = (tid < ntrip);
    if (t0v) {
        float4 A = fus4[3 * tid], Bq = fus4[3 * tid + 1], Cq = fus4[3 * tid + 2];
        k0 = __float_as_uint(d2_ref(vx, vy, vz, A.x,  A.y,  A.z));
        k1 = __float_as_uint(d2_ref(vx, vy, vz, A.w,  Bq.x, Bq.y));
        k2 = __float_as_uint(d2_ref(vx, vy, vz, Bq.z, Bq.w, Cq.x));
        k3 = __float_as_uint(d2_ref(vx, vy, vz, Cq.y, Cq.z, Cq.w));
        atomicAdd(&hist2[bank][k0 >> 21], 1u);
        atomicAdd(&hist2[bank][k1 >> 21], 1u);
        atomicAdd(&hist2[bank][k2 >> 21], 1u);
        atomicAdd(&hist2[bank][k3 >> 21], 1u);
    }
    __syncthreads();

    // ---- E: conservative upper-bound bucket for the KTOP-th key, from the sample ----
    unsigned srank;
    {
        long long sample = (long long)((ntrip < BLOCK) ? ntrip : BLOCK) * 4;
        if (sample >= (long long)nfus) {
            srank = KTOP;  // sample is the whole population -> exact
        } else {
            unsigned s2 = (unsigned)(((long long)3 * KTOP * sample + nfus - 1) / nfus);
            srank = (s2 < SRANK_MIN) ? SRANK_MIN : s2;
        }
    }
    find_bucket(srank);
    const unsigned E = (s_bucket < NHIST) ? s_bucket : (NHIST - 1);  // unset -> no filtering
    // all keys <= maxKey lie in buckets <= E (positive-float bit order == value order)
    const unsigned maxKey = ((E + 1u) << 21) - 1u;

    // sample keys: wave-aggregated push of qualifiers (t0v drops high lanes first)
    if (t0v) agg_push4(k0, k1, k2, k3, maxKey, 4u * (unsigned)tid);

    // ---- main stream: 1 uint compare per key; wave-aggregated push; prefetch next trip ----
    {
        int m = BLOCK + tid;
        bool valid = (m < ntrip);
        float4 A, Bq, Cq;
        if (valid) { A = fus4[3 * m]; Bq = fus4[3 * m + 1]; Cq = fus4[3 * m + 2]; }
        while (valid) {
            const int mn = m + BLOCK;
            const bool vnext = (mn < ntrip);
            float4 An, Bn, Cn;
            if (vnext) { An = fus4[3 * mn]; Bn = fus4[3 * mn + 1]; Cn = fus4[3 * mn + 2]; }

            unsigned q0k = __float_as_uint(d2_ref(vx, vy, vz, A.x,  A.y,  A.z));
            unsigned q1k = __float_as_uint(d2_ref(vx, vy, vz, A.w,  Bq.x, Bq.y));
            unsigned q2k = __float_as_uint(d2_ref(vx, vy, vz, Bq.z, Bq.w, Cq.x));
            unsigned q3k = __float_as_uint(d2_ref(vx, vy, vz, Cq.y, Cq.z, Cq.w));
            // loop-exit drops HIGH lanes first (m grows with lane) => lane 0 active
            // whenever any lane is, so agg_push4's lane-0 atomic is safe.
            agg_push4(q0k, q1k, q2k, q3k, maxKey, 4u * (unsigned)m);
            A = An; Bq = Bn; Cq = Cn; m = mn; valid = vnext;
        }
    }
    // tail (nfus % 4): at most 3 points, per-lane push
    for (int j = (nfus & ~3) + tid; j < nfus; j += BLOCK) {
        unsigned k = key_of(fus, j, vx, vy, vz);
        if (k <= maxKey) push_l(k, (unsigned)j);
    }
    __syncthreads();

    // ---- rebuild exact hist on [0, E] from clist (no overflow => clist is the exact
    //      multiset of keys with bucket <= E, sample included) ----
    const int cnRaw = s_clistCount;
    const bool noOvf = (cnRaw <= CLIST_CAP);
    if (noOvf) {
        for (int i = tid; i <= (int)E; i += BLOCK) { hist2[0][i] = 0; hist2[1][i] = 0; }
        __syncthreads();
        for (int i = tid; i < cnRaw; i += BLOCK)
            atomicAdd(&hist2[bank][(unsigned)(clist[i] >> 53)], 1u);
        __syncthreads();
    }

    // hist exact on [0, E]; garbage (sample-only) above E. A crossing at T <= E is exact.
    find_bucket(KTOP);
    unsigned T = s_bucket;
    unsigned rem = s_rem;
    unsigned bcount = s_bcount;
    int shift = 21;
    const bool fastOK = noOvf && (T <= E);

    if (!fastOK) {
        // rare: bound E failed or clist overflowed -> rebuild full exact histogram + argmin
        for (int i = tid; i < NHIST; i += BLOCK) { hist2[0][i] = 0; hist2[1][i] = 0; }
        __syncthreads();
        unsigned long long lm = ~0ull;
        for (int j = tid; j < nfus; j += BLOCK) {
            unsigned k = key_of(fus, j, vx, vy, vz);
            atomicAdd(&hist2[bank][k >> 21], 1u);
            unsigned long long p = ((unsigned long long)k << 32) | (unsigned)j;
            lm = (p < lm) ? p : lm;
        }
        #pragma unroll
        for (int d = 32; d > 0; d >>= 1) {
            unsigned long long o = __shfl_xor(lm, d, 64);
            lm = (o < lm) ? o : lm;
        }
        if (lane == 0) atomicMin(&s_minPacked, lm);
        __syncthreads();
        find_bucket(KTOP);
        T = s_bucket; rem = s_rem; bcount = s_bcount;
    } else if (bcount > CAND_CAP) {
        // rare: refine will trigger -> fused scan below won't run; compute argmin now
        unsigned long long lm = ~0ull;
        for (int i = tid; i < cnRaw; i += BLOCK) { unsigned long long p = clist[i]; lm = (p < lm) ? p : lm; }
        #pragma unroll
        for (int d = 32; d > 0; d >>= 1) {
            unsigned long long o = __shfl_xor(lm, d, 64);
            lm = (o < lm) ? o : lm;
        }
        if (lane == 0) atomicMin(&s_minPacked, lm);
        __syncthreads();
    }

    // ---- rare: refine threshold bucket if too many candidates (reload-based) ----
    while (bcount > CAND_CAP && shift > 0) {
        int newshift = (shift > 11) ? (shift - 11) : 0;
        unsigned digmask = (1u << (shift - newshift)) - 1;
        for (int i = tid; i < NHIST; i += BLOCK) { hist2[0][i] = 0; hist2[1][i] = 0; }
        __syncthreads();
        for (int j = tid; j < nfus; j += BLOCK) {
            unsigned k = key_of(fus, j, vx, vy, vz);
            if ((k >> shift) == T) atomicAdd(&hist2[bank][(k >> newshift) & digmask], 1u);
        }
        __syncthreads();
        find_bucket(rem);
        T = (T << (shift - newshift)) | s_bucket;
        rem = s_rem;
        bcount = s_bcount;
        shift = newshift;
    }

    // ---- scan B fused with argmin: one pass over clist, wave-aggregated pushes ----
    if (fastOK && shift == 21) {
        unsigned long long lm = ~0ull;
        for (int i = tid; i < cnRaw; i += BLOCK) {
            unsigned long long p = clist[i];
            lm = (p < lm) ? p : lm;
            unsigned hi = (unsigned)(p >> 53);   // == key >> 21
            bool isw = (hi < T), isc = (hi == T);
            // high lanes exit this loop first => lane 0 active whenever any lane is
            unsigned long long mw = __ballot(isw), mc = __ballot(isc);
            if (mw | mc) {
                int cw = __popcll(mw), cc = __popcll(mc);
                int bw = 0, bc = 0;
                if (lane == 0) {
                    if (cw) bw = atomicAdd(&s_wcount, cw);
                    if (cc) bc = atomicAdd(&s_candCount, cc);
                }
                bw = __shfl(bw, 0, 64); bc = __shfl(bc, 0, 64);
                const unsigned long long lt = (1ull << lane) - 1ull;
                if (isw) { int pos = bw + (int)__popcll(mw & lt); if (pos < WCAP) wlist[pos] = (int)(p & 0xFFFFFFFFull); }
                if (isc) { int pos = bc + (int)__popcll(mc & lt); if (pos < CAND_CAP) cand[pos] = p; }
            }
        }
        #pragma unroll
        for (int d = 32; d > 0; d >>= 1) {
            unsigned long long o = __shfl_xor(lm, d, 64);
            lm = (o < lm) ? o : lm;
        }
        if (lane == 0) atomicMin(&s_minPacked, lm);
    } else {
        for (int j = tid; j < nfus; j += BLOCK) {
            unsigned k = key_of(fus, j, vx, vy, vz);
            unsigned hi = k >> shift;
            if (hi < T) { int pos = atomicAdd(&s_wcount, 1); if (pos < WCAP) wlist[pos] = j; }
            else if (hi == T) { int pos = atomicAdd(&s_candCount, 1); if (pos < CAND_CAP) cand[pos] = ((unsigned long long)k << 32) | (unsigned)j; }
        }
    }
    __syncthreads();

    const int cnt = s_candCount;
    // tid 0 issues the q0 global load; its ~500-cycle latency hides under the rank loop
    // (rank is independent of q0). s_minPacked is final in every path by this barrier.
    if (tid == 0) {
        int idx0 = (int)(s_minPacked & 0xFFFFFFFFull);
        s_q0[0] = fus[idx0 * 3]; s_q0[1] = fus[idx0 * 3 + 1]; s_q0[2] = fus[idx0 * 3 + 2];
    }
    if (cnt <= CAND_CAP) {
        // exact stable ranking among boundary candidates by (key, idx); qualifiers join wlist
        for (int i = tid; i < cnt; i += BLOCK) {
            unsigned long long me = cand[i];
            int rank = 0;
            for (int k2i = 0; k2i < cnt; k2i++) rank += (cand[k2i] < me) ? 1 : 0;
            if (rank < (int)rem) {
                int pos = atomicAdd(&s_wcount, 1);
                if (pos < WCAP) wlist[pos] = (int)(me & 0xFFFFFFFFull);
            }
        }
    }
    __syncthreads();
    const float q0x = s_q0[0], q0y = s_q0[1], q0z = s_q0[2];

    // ---- compact winner processing: ~one compute_bin per thread ----
    {
        int wc = s_wcount; if (wc > WCAP) wc = WCAP;
        for (int i = tid; i < wc; i += BLOCK) {
            int j = wlist[i];
            float fxs = fus[3 * j], fys = fus[3 * j + 1], fzs = fus[3 * j + 2];
            int bin = compute_bin(__fsub_rn(fxs, q0x), __fsub_rn(fys, q0y), __fsub_rn(fzs, q0z));
            if (bin >= 0 && bin < NPART) atomicAdd(&hist32[bin], 1u);
        }
    }
    __syncthreads();

    if (cnt > CAND_CAP) {
        // pathological fallback: serial extraction of `rem` smallest packed (key,idx) in bucket T
        if (tid == 0) s_lowBound = 0;
        __syncthreads();
        for (unsigned itx = 0; itx < rem; ++itx) {
            if (tid == 0) s_minPacked = ~0ull;
            __syncthreads();
            unsigned long long lowB = s_lowBound;
            unsigned long long lm = ~0ull;
            for (int j = tid; j < nfus; j += BLOCK) {
                unsigned k = key_of(fus, j, vx, vy, vz);
                if ((k >> shift) == T) {
                    unsigned long long p = ((unsigned long long)k << 32) | (unsigned)j;
                    if (p >= lowB && p < lm) lm = p;
                }
            }
            #pragma unroll
            for (int d = 32; d > 0; d >>= 1) {
                unsigned long long o = __shfl_xor(lm, d, 64);
                lm = (o < lm) ? o : lm;
            }
            if (lane == 0) atomicMin(&s_minPacked, lm);
            __syncthreads();
            if (tid == 0) {
                int jm = (int)(s_minPacked & 0xFFFFFFFFull);
                float fxs = fus[jm * 3], fys = fus[jm * 3 + 1], fzs = fus[jm * 3 + 2];
                int bin = compute_bin(__fsub_rn(fxs, q0x), __fsub_rn(fys, q0y), __fsub_rn(fzs, q0z));
                if (bin >= 0 && bin < NPART) hist32[bin] += 1u;
                s_lowBound = s_minPacked + 1;
            }
            __syncthreads();
        }
    }

    // ---- epilogue (32 lanes of wave 0): counts+1 -> L2-normalize*4 -> softmax ----
    if (tid < NPART) {
        float c = (float)hist32[tid] + 1.0f;
        float ss = __fmul_rn(c, c);
        #pragma unroll
        for (int d = 16; d > 0; d >>= 1) ss += __shfl_xor(ss, d, 64);
        float v = __fmul_rn(__fdiv_rn(c, sqrtf(ss)), 4.0f);
        float mx = v;
        #pragma unroll
        for (int d = 16; d > 0; d >>= 1) mx = fmaxf(mx, __shfl_xor(mx, d, 64));
        float e = expf(v - mx);
        float sum = e;
        #pragma unroll
        for (int d = 16; d > 0; d >>= 1) sum += __shfl_xor(sum, d, 64);
        out[b * NPART + tid] = __fdiv_rn(e, sum);
    }
}

extern "C" void kernel_launch(void* const* d_in, const int* in_sizes, int n_in,
                              void* d_out, int out_size, void* d_ws, size_t ws_size,
                              hipStream_t stream) {
    const float* veh = (const float*)d_in[0];   // (1024, 3)
    const float* fus = (const float*)d_in[1];   // (20000, 3)
    float* out = (float*)d_out;                 // (1024, 32)
    int nveh = in_sizes[0] / 3;
    int nfus = in_sizes[1] / 3;
    shape_context_kernel<<<nveh, BLOCK, 0, stream>>>(veh, fus, out, nfus);
}